// Round 2
// baseline (2237.974 us; speedup 1.0000x reference)
//
#include <hip/hip_runtime.h>
#include <math.h>

// Problem dims
#define TT 100
#define BB 64
#define II 256
#define HH 512
#define G4H 2048   // 4H
#define G3H 1536   // 3H
#define NBLK 256   // persistent recurrence blocks (= HH/2)

// ---- workspace layout (float offsets) ----
// G_T   [T][4H][B]   gates from x@Wih^T + biases, layout [t][j][b]
// DbufT [B][T][3H]   (aliases G_T region after step loop — G_T dead by then)
// Hbuf  [T+1][H][B]  h history transposed; slot 0 = initial_h^T
// Fbuf  [T][H][B]    f gates
// Dbuf  [T][3H][B]   d values (scaled in-place to \tilde{d})
// cT    [H][B]
// xT    [T][I][B]    (WhhG aliases xT region after gx GEMM — xT dead by then)
// WihT  [I][4H]      (bar[] aliases WihT after gx GEMM — WihT dead by then)
// WhhT  [H][4H]
#define OFF_GT    0
#define OFF_HBUF  13107200
#define OFF_FBUF  16416768
#define OFF_DBUF  19693568
#define OFF_CT    29523968
#define OFF_XT    29556736
#define OFF_WIHT  31195136
#define OFF_WHHT  31719424

// ---- output layout (float offsets in d_out) ----
#define O_OUT   0          // outputs [T][B][H]
#define O_CX    3276800    // cx [B][H]
#define O_EVIH  3309568    // ev_ih [B][3H][I]
#define O_EVHH  28475392   // ev_hh [B][3H][H]
#define O_EVB   78807040   // ev_b  [B][3H]

// Generic 64x64 tiled transpose: dst[c][r] = src[r][c]. R,C multiples of 64.
__global__ __launch_bounds__(256) void tp64(const float* __restrict__ src,
                                            float* __restrict__ dst,
                                            int R, int C,
                                            long sstride, long dstride) {
  __shared__ float tile[64][65];
  src += (long)blockIdx.z * sstride;
  dst += (long)blockIdx.z * dstride;
  int r0 = blockIdx.y * 64, c0 = blockIdx.x * 64;
  int tx = threadIdx.x & 15, tq = threadIdx.x >> 4;
#pragma unroll
  for (int p = 0; p < 4; ++p) {
    int rl = p * 16 + tq;
    float4 v = *(const float4*)(src + (long)(r0 + rl) * C + c0 + tx * 4);
    tile[rl][tx * 4 + 0] = v.x; tile[rl][tx * 4 + 1] = v.y;
    tile[rl][tx * 4 + 2] = v.z; tile[rl][tx * 4 + 3] = v.w;
  }
  __syncthreads();
#pragma unroll
  for (int p = 0; p < 4; ++p) {
    int cl = p * 16 + tq;
    float4 v;
    v.x = tile[tx * 4 + 0][cl]; v.y = tile[tx * 4 + 1][cl];
    v.z = tile[tx * 4 + 2][cl]; v.w = tile[tx * 4 + 3][cl];
    *(float4*)(dst + (long)(c0 + cl) * R + r0 + tx * 4) = v;
  }
}

// WhhG[k][hh*4+g] = WhhT[k][g*512+hh]  (gate-interleaved for uniform dwordx4)
// Also zeroes the barrier slots (bar aliases dead WihT) for this replay.
__global__ __launch_bounds__(256) void make_whhg(const float* __restrict__ WhhT,
                                                 float* __restrict__ WhhG,
                                                 int* __restrict__ bar) {
  int gid = blockIdx.x * 256 + threadIdx.x;  // 512*2048 total
  if (gid < NBLK) bar[gid] = 0;
  int k = gid >> 11, j = gid & 2047;
  float v = WhhT[gid];
  WhhG[(long)k * G4H + ((j & 511) << 2) + (j >> 9)] = v;
}

// Tiled TN GEMM: C[m][n] = sum_k A[k][m] * Z[k][n]  (+ bias[m] if BIAS).
// Both operands stored K-major. 64x64 C-tile, 256 thr, 4x4 outputs/thread.
// ZSHIFT: Z row k maps to (k==0 ? Z0 : Z + (k-1)*ldz)  [for h_{t-1} history].
template <int BK, int KTILES, bool BIAS, bool ZSHIFT>
__global__ __launch_bounds__(256) void gemm_tn(
    const float* __restrict__ A, long batchA, int lda,
    const float* __restrict__ Z, long batchZ, int ldz,
    const float* __restrict__ Z0, long batchZ0,
    float* __restrict__ C, long batchC, int ldc,
    const float* __restrict__ bia, const float* __restrict__ bib) {
  __shared__ float As[BK][64];
  __shared__ float Zs[BK][64];
  int tid = threadIdx.x;
  int tn = tid & 15, tm = tid >> 4;
  int m0 = blockIdx.x * 64, n0 = blockIdx.y * 64;
  long bz = blockIdx.z;
  const float* Ab = A + bz * batchA + m0;
  const float* Zb = Z + bz * batchZ + n0;
  const float* Z0b = ZSHIFT ? (Z0 + bz * batchZ0 + n0) : nullptr;
  float acc[4][4] = {};
  for (int kt = 0; kt < KTILES; ++kt) {
    int k0 = kt * BK;
#pragma unroll
    for (int p = tid; p < BK * 64; p += 256) {
      int r = p >> 6, c = p & 63;
      int k = k0 + r;
      As[r][c] = Ab[(long)k * lda + c];
      const float* zr;
      if (ZSHIFT)
        zr = (k == 0) ? Z0b : (Zb + (long)(k - 1) * ldz);
      else
        zr = Zb + (long)k * ldz;
      Zs[r][c] = zr[c];
    }
    __syncthreads();
#pragma unroll 4
    for (int kk = 0; kk < BK; ++kk) {
      float4 a = *(const float4*)&As[kk][tm * 4];
      float4 z = *(const float4*)&Zs[kk][tn * 4];
      float av[4] = {a.x, a.y, a.z, a.w};
      float zv[4] = {z.x, z.y, z.z, z.w};
#pragma unroll
      for (int q = 0; q < 4; ++q)
#pragma unroll
        for (int r = 0; r < 4; ++r)
          acc[q][r] = fmaf(av[q], zv[r], acc[q][r]);
    }
    __syncthreads();
  }
  float* Cb = C + bz * batchC + n0 + tn * 4;
#pragma unroll
  for (int q = 0; q < 4; ++q) {
    int m = m0 + tm * 4 + q;
    float bv = BIAS ? (bia[m] + bib[m]) : 0.f;
    float4 v;
    v.x = acc[q][0] + bv; v.y = acc[q][1] + bv;
    v.z = acc[q][2] + bv; v.w = acc[q][3] + bv;
    *(float4*)(Cb + (long)m * ldc) = v;
  }
}

// ---- Persistent fused recurrence: all 100 steps in ONE kernel. ----
// Launched via hipLaunchCooperativeKernel => all 256 blocks guaranteed
// co-resident (2 blocks/CU under __launch_bounds__(512,4)).
// 256 blocks x 512 thr (8 waves). Block bx owns hh pair (2bx, 2bx+1).
// Wave w = k-partition (64 k each); every wave computes BOTH hh (8 accs).
// WhhG addresses are wave-uniform -> scalar s_load path, sL1-resident.
// c lives in registers (tid<128). Per-step device barrier: per-block
// release-store slot + wave-0 poll of all 256 slots + acquire fence.
// Hbuf[t+1] is a fresh address each step -> no stale-line hazard; release
// (wbl2) / acquire (inv) cover cross-XCD visibility.
__global__ __launch_bounds__(512, 4) void lstm_rec(
    const float* __restrict__ G_T, const float* __restrict__ WhhG,
    float* __restrict__ Hbuf, float* __restrict__ cT,
    float* __restrict__ Fbuf, float* __restrict__ Dbuf,
    int* __restrict__ bar) {
  __shared__ float red[8][8][64];  // [kp][gate-row j][b]
  int tid = threadIdx.x;
  int lane = tid & 63;
  int wave = __builtin_amdgcn_readfirstlane(tid >> 6);  // 0..7 = k-partition
  int bx = blockIdx.x;
  const float* wp = WhhG + (long)(wave * 64) * G4H + bx * 8;
  int h2 = tid >> 6;  // 0/1 for tid<128
  int b = tid & 63;
  float creg = 0.f;
  if (tid < 128) creg = cT[(bx * 2 + h2) * BB + b];

  // Prefetch step-0 x-gate precomputes (G_T is static during this kernel).
  float gpre0 = 0.f, gpre1 = 0.f, gpre2 = 0.f, gpre3 = 0.f;
  if (tid < 128) {
    const float* gp = G_T + (bx * 2 + h2) * BB + b;
    gpre0 = gp[0l * HH * BB];
    gpre1 = gp[1l * HH * BB];
    gpre2 = gp[2l * HH * BB];
    gpre3 = gp[3l * HH * BB];
  }

  for (int t = 0; t < TT; ++t) {
    // Partial dot products over this wave's 64 k, both hh, 4 gates each.
    const float* hp = Hbuf + (long)t * (HH * BB) + (wave * 64) * BB + lane;
    float a0 = 0.f, a1 = 0.f, a2 = 0.f, a3 = 0.f;
    float a4 = 0.f, a5 = 0.f, a6 = 0.f, a7 = 0.f;
#pragma unroll 4
    for (int k = 0; k < 64; ++k) {
      float h = hp[(long)k * BB];
      float4 w0 = *(const float4*)(wp + (long)k * G4H);
      float4 w1 = *(const float4*)(wp + (long)k * G4H + 4);
      a0 = fmaf(w0.x, h, a0); a1 = fmaf(w0.y, h, a1);
      a2 = fmaf(w0.z, h, a2); a3 = fmaf(w0.w, h, a3);
      a4 = fmaf(w1.x, h, a4); a5 = fmaf(w1.y, h, a5);
      a6 = fmaf(w1.z, h, a6); a7 = fmaf(w1.w, h, a7);
    }
    red[wave][0][lane] = a0; red[wave][1][lane] = a1;
    red[wave][2][lane] = a2; red[wave][3][lane] = a3;
    red[wave][4][lane] = a4; red[wave][5][lane] = a5;
    red[wave][6][lane] = a6; red[wave][7][lane] = a7;
    __syncthreads();
    if (tid < 128) {
      float g0 = gpre0, g1 = gpre1, g2 = gpre2, g3 = gpre3;
#pragma unroll
      for (int kp = 0; kp < 8; ++kp) {
        g0 += red[kp][h2 * 4 + 0][b];
        g1 += red[kp][h2 * 4 + 1][b];
        g2 += red[kp][h2 * 4 + 2][b];
        g3 += red[kp][h2 * 4 + 3][b];
      }
      float ig = 1.f / (1.f + expf(-g0));
      float fg = 1.f / (1.f + expf(-g1));
      float gg = tanhf(g2);
      float og = 1.f / (1.f + expf(-g3));
      int idx = (bx * 2 + h2) * BB + b;
      float co = creg;
      float cy = fg * co + ig * gg;
      creg = cy;
      Hbuf[(long)(t + 1) * (HH * BB) + idx] = og * tanhf(cy);
      Fbuf[(long)t * (HH * BB) + idx] = fg;
      float* dp = Dbuf + (long)t * (G3H * BB) + idx;
      dp[0] = gg * ig * (1.f - ig);
      dp[HH * BB] = co * fg * (1.f - fg);
      dp[2 * HH * BB] = ig * (1.f - gg * gg);
    }
    // Drain all waves' stores (syncthreads implies vmcnt(0) before s_barrier),
    // then signal + prefetch next gpre + wait. Skip barrier after last step.
    __syncthreads();
    if (t < TT - 1) {
      if (tid == 0)
        __hip_atomic_store(&bar[bx], t + 1, __ATOMIC_RELEASE,
                           __HIP_MEMORY_SCOPE_AGENT);
      // Prefetch next step's x-gate precomputes; latency hides under the
      // barrier propagation (issued AFTER the release so its vmcnt drain
      // doesn't wait on these loads).
      if (tid < 128) {
        const float* gp =
            G_T + (long)(t + 1) * (G4H * BB) + (bx * 2 + h2) * BB + b;
        gpre0 = gp[0l * HH * BB];
        gpre1 = gp[1l * HH * BB];
        gpre2 = gp[2l * HH * BB];
        gpre3 = gp[3l * HH * BB];
      }
      if (tid < 64) {
        int tgt = t + 1;
        bool ok;
        do {
          int v0 = __hip_atomic_load(&bar[lane], __ATOMIC_RELAXED,
                                     __HIP_MEMORY_SCOPE_AGENT);
          int v1 = __hip_atomic_load(&bar[lane + 64], __ATOMIC_RELAXED,
                                     __HIP_MEMORY_SCOPE_AGENT);
          int v2 = __hip_atomic_load(&bar[lane + 128], __ATOMIC_RELAXED,
                                     __HIP_MEMORY_SCOPE_AGENT);
          int v3 = __hip_atomic_load(&bar[lane + 192], __ATOMIC_RELAXED,
                                     __HIP_MEMORY_SCOPE_AGENT);
          ok = (v0 >= tgt) && (v1 >= tgt) && (v2 >= tgt) && (v3 >= tgt);
          if (!__all(ok)) __builtin_amdgcn_s_sleep(1);
          else break;
        } while (true);
        __builtin_amdgcn_fence(__ATOMIC_ACQUIRE, "agent");
      }
      __syncthreads();
    }
  }
  if (tid < 128) cT[(bx * 2 + h2) * BB + b] = creg;
}

// Backward suffix scan: Dbuf[t] *= P_t; also emits ev_b.
__global__ __launch_bounds__(256) void suffix_scale(float* __restrict__ Dbuf,
                                                    const float* __restrict__ Fbuf,
                                                    float* __restrict__ evb) {
  int g = blockIdx.x * 256 + threadIdx.x;
  int b = g & 63, hh = g >> 6;
  float P = 1.f, e0 = 0.f, e1 = 0.f, e2 = 0.f;
#pragma unroll 2
  for (int t = TT - 1; t >= 0; --t) {
    float* dp = Dbuf + (long)t * (G3H * BB) + hh * BB + b;
    float v0 = dp[0] * P, v1 = dp[HH * BB] * P, v2 = dp[2 * HH * BB] * P;
    dp[0] = v0; dp[HH * BB] = v1; dp[2 * HH * BB] = v2;
    e0 += v0; e1 += v1; e2 += v2;
    P *= Fbuf[(long)t * (HH * BB) + hh * BB + b];
  }
  evb[b * G3H + hh] = e0;
  evb[b * G3H + HH + hh] = e1;
  evb[b * G3H + 2 * HH + hh] = e2;
}

extern "C" void kernel_launch(void* const* d_in, const int* in_sizes, int n_in,
                              void* d_out, int out_size, void* d_ws, size_t ws_size,
                              hipStream_t stream) {
  const float* x   = (const float*)d_in[0];  // [T][B][I]
  const float* h0  = (const float*)d_in[1];  // [B][H]
  const float* c0  = (const float*)d_in[2];  // [B][H]
  const float* Wih = (const float*)d_in[3];  // [4H][I]
  const float* Whh = (const float*)d_in[4];  // [4H][H]
  const float* bih = (const float*)d_in[5];
  const float* bhh = (const float*)d_in[6];
  float* out = (float*)d_out;
  float* ws = (float*)d_ws;

  float* G_T   = ws + OFF_GT;
  float* DbufT = ws + OFF_GT;    // aliases G_T (G_T dead after step loop)
  float* Hbuf  = ws + OFF_HBUF;
  float* Fbuf  = ws + OFF_FBUF;
  float* Dbuf  = ws + OFF_DBUF;
  float* cT    = ws + OFF_CT;
  float* xT    = ws + OFF_XT;
  float* WhhG  = ws + OFF_XT;    // aliases xT (xT dead after gx GEMM)
  float* WihT  = ws + OFF_WIHT;
  int*   bar   = (int*)(ws + OFF_WIHT);  // aliases WihT (dead after gx GEMM)
  float* WhhT  = ws + OFF_WHHT;

  // ---- prep transposes ----
  tp64<<<dim3(II / 64, G4H / 64, 1), 256, 0, stream>>>(Wih, WihT, G4H, II, 0, 0);
  tp64<<<dim3(HH / 64, G4H / 64, 1), 256, 0, stream>>>(Whh, WhhT, G4H, HH, 0, 0);
  tp64<<<dim3(II / 64, 1, TT), 256, 0, stream>>>(x, xT, BB, II, BB * II, BB * II);
  tp64<<<dim3(HH / 64, 1, 1), 256, 0, stream>>>(h0, Hbuf, BB, HH, 0, 0);
  tp64<<<dim3(HH / 64, 1, 1), 256, 0, stream>>>(c0, cT, BB, HH, 0, 0);

  // ---- G = x @ Wih^T + biases, layout [t][j][b] ----
  // C[m=j 2048][n=b 64] = sum_k WihT[k][j] * xT[t][k][b], K=256
  gemm_tn<64, 4, true, false><<<dim3(G4H / 64, 1, TT), 256, 0, stream>>>(
      WihT, 0, G4H, xT, (long)II * BB, BB, nullptr, 0,
      G_T, (long)G4H * BB, BB, bih, bhh);

  // ---- gate-interleave Whh + zero barrier slots (after gx: WihT/xT dead) ----
  make_whhg<<<dim3(HH * G4H / 256, 1, 1), 256, 0, stream>>>(WhhT, WhhG, bar);

  // ---- fused sequential recurrence: ONE cooperative kernel, 100 steps ----
  {
    const float* a_gt = G_T;
    const float* a_wg = WhhG;
    float* a_hb = Hbuf;
    float* a_ct = cT;
    float* a_fb = Fbuf;
    float* a_db = Dbuf;
    int* a_bar = bar;
    void* args[] = {(void*)&a_gt, (void*)&a_wg, (void*)&a_hb, (void*)&a_ct,
                    (void*)&a_fb, (void*)&a_db, (void*)&a_bar};
    hipLaunchCooperativeKernel((const void*)lstm_rec, dim3(NBLK), dim3(512),
                               args, 0, stream);
  }

  // ---- backward suffix scaling (+ ev_b) ----
  suffix_scale<<<dim3(HH * BB / 256, 1, 1), 256, 0, stream>>>(Dbuf, Fbuf,
                                                              out + O_EVB);

  // ---- Dbuf [T*3H][B] -> DbufT [B][T*3H] (into dead G_T region) ----
  tp64<<<dim3(1, TT * G3H / 64, 1), 256, 0, stream>>>(Dbuf, DbufT, TT * G3H, BB,
                                                      0, 0);

  // ---- outputs + cx ----
  tp64<<<dim3(1, HH / 64, TT), 256, 0, stream>>>(Hbuf + HH * BB, out + O_OUT,
                                                 HH, BB, HH * BB, HH * BB);
  tp64<<<dim3(1, HH / 64, 1), 256, 0, stream>>>(cT, out + O_CX, HH, BB, 0, 0);

  // ---- ev_ih[b][j][i] = sum_t DbufT[b][t][j] * x[t][b][i], K=100 ----
  gemm_tn<20, 5, false, false><<<dim3(G3H / 64, II / 64, BB), 256, 0, stream>>>(
      DbufT, (long)TT * G3H, G3H, x, (long)II, (long)BB * II, nullptr, 0,
      out + O_EVIH, (long)G3H * II, II, nullptr, nullptr);

  // ---- ev_hh[b][j][k] = sum_t DbufT[b][t][j] * h_{t-1}[b][k], K=100 ----
  gemm_tn<20, 5, false, true><<<dim3(G3H / 64, HH / 64, BB), 256, 0, stream>>>(
      DbufT, (long)TT * G3H, G3H, out + O_OUT, (long)HH, (long)BB * HH,
      h0, (long)HH,
      out + O_EVHH, (long)G3H * HH, HH, nullptr, nullptr);
}

// Round 3
// 1544.891 us; speedup vs baseline: 1.4486x; 1.4486x over previous
//
#include <hip/hip_runtime.h>
#include <math.h>

// Problem dims
#define TT 100
#define BB 64
#define II 256
#define HH 512
#define G4H 2048   // 4H
#define G3H 1536   // 3H
#define NBLK 256   // persistent recurrence blocks (= HH/2)

// ---- workspace layout (float offsets) ----
// G_T   [T][4H][B]   gates from x@Wih^T + biases, layout [t][j][b]
// DbufT [B][T][3H]   (aliases G_T region after step loop — G_T dead by then)
// Hbuf  [T+1][H][B]  h history transposed; slot 0 = initial_h^T
// Fbuf  [T][H][B]    f gates
// Dbuf  [T][3H][B]   d values (scaled in-place to \tilde{d})
// cT    [H][B]
// xT    [T][I][B]    (WhhG aliases xT region after gx GEMM — xT dead by then)
// WihT  [I][4H]      (bar[] aliases WihT after gx GEMM — WihT dead by then)
// WhhT  [H][4H]
#define OFF_GT    0
#define OFF_HBUF  13107200
#define OFF_FBUF  16416768
#define OFF_DBUF  19693568
#define OFF_CT    29523968
#define OFF_XT    29556736
#define OFF_WIHT  31195136
#define OFF_WHHT  31719424

// ---- output layout (float offsets in d_out) ----
#define O_OUT   0          // outputs [T][B][H]
#define O_CX    3276800    // cx [B][H]
#define O_EVIH  3309568    // ev_ih [B][3H][I]
#define O_EVHH  28475392   // ev_hh [B][3H][H]
#define O_EVB   78807040   // ev_b  [B][3H]

// Generic 64x64 tiled transpose: dst[c][r] = src[r][c]. R,C multiples of 64.
__global__ __launch_bounds__(256) void tp64(const float* __restrict__ src,
                                            float* __restrict__ dst,
                                            int R, int C,
                                            long sstride, long dstride) {
  __shared__ float tile[64][65];
  src += (long)blockIdx.z * sstride;
  dst += (long)blockIdx.z * dstride;
  int r0 = blockIdx.y * 64, c0 = blockIdx.x * 64;
  int tx = threadIdx.x & 15, tq = threadIdx.x >> 4;
#pragma unroll
  for (int p = 0; p < 4; ++p) {
    int rl = p * 16 + tq;
    float4 v = *(const float4*)(src + (long)(r0 + rl) * C + c0 + tx * 4);
    tile[rl][tx * 4 + 0] = v.x; tile[rl][tx * 4 + 1] = v.y;
    tile[rl][tx * 4 + 2] = v.z; tile[rl][tx * 4 + 3] = v.w;
  }
  __syncthreads();
#pragma unroll
  for (int p = 0; p < 4; ++p) {
    int cl = p * 16 + tq;
    float4 v;
    v.x = tile[tx * 4 + 0][cl]; v.y = tile[tx * 4 + 1][cl];
    v.z = tile[tx * 4 + 2][cl]; v.w = tile[tx * 4 + 3][cl];
    *(float4*)(dst + (long)(c0 + cl) * R + r0 + tx * 4) = v;
  }
}

// WhhG[k][hh*4+g] = WhhT[k][g*512+hh]  (gate-interleaved for uniform dwordx4)
// Also zeroes the barrier slots (bar aliases dead WihT) for this replay.
__global__ __launch_bounds__(256) void make_whhg(const float* __restrict__ WhhT,
                                                 float* __restrict__ WhhG,
                                                 int* __restrict__ bar) {
  int gid = blockIdx.x * 256 + threadIdx.x;  // 512*2048 total
  if (gid < NBLK) bar[gid] = 0;
  int k = gid >> 11, j = gid & 2047;
  float v = WhhT[gid];
  WhhG[(long)k * G4H + ((j & 511) << 2) + (j >> 9)] = v;
}

// Tiled TN GEMM: C[m][n] = sum_k A[k][m] * Z[k][n]  (+ bias[m] if BIAS).
// Both operands stored K-major. 64x64 C-tile, 256 thr, 4x4 outputs/thread.
// ZSHIFT: Z row k maps to (k==0 ? Z0 : Z + (k-1)*ldz)  [for h_{t-1} history].
template <int BK, int KTILES, bool BIAS, bool ZSHIFT>
__global__ __launch_bounds__(256) void gemm_tn(
    const float* __restrict__ A, long batchA, int lda,
    const float* __restrict__ Z, long batchZ, int ldz,
    const float* __restrict__ Z0, long batchZ0,
    float* __restrict__ C, long batchC, int ldc,
    const float* __restrict__ bia, const float* __restrict__ bib) {
  __shared__ float As[BK][64];
  __shared__ float Zs[BK][64];
  int tid = threadIdx.x;
  int tn = tid & 15, tm = tid >> 4;
  int m0 = blockIdx.x * 64, n0 = blockIdx.y * 64;
  long bz = blockIdx.z;
  const float* Ab = A + bz * batchA + m0;
  const float* Zb = Z + bz * batchZ + n0;
  const float* Z0b = ZSHIFT ? (Z0 + bz * batchZ0 + n0) : nullptr;
  float acc[4][4] = {};
  for (int kt = 0; kt < KTILES; ++kt) {
    int k0 = kt * BK;
#pragma unroll
    for (int p = tid; p < BK * 64; p += 256) {
      int r = p >> 6, c = p & 63;
      int k = k0 + r;
      As[r][c] = Ab[(long)k * lda + c];
      const float* zr;
      if (ZSHIFT)
        zr = (k == 0) ? Z0b : (Zb + (long)(k - 1) * ldz);
      else
        zr = Zb + (long)k * ldz;
      Zs[r][c] = zr[c];
    }
    __syncthreads();
#pragma unroll 4
    for (int kk = 0; kk < BK; ++kk) {
      float4 a = *(const float4*)&As[kk][tm * 4];
      float4 z = *(const float4*)&Zs[kk][tn * 4];
      float av[4] = {a.x, a.y, a.z, a.w};
      float zv[4] = {z.x, z.y, z.z, z.w};
#pragma unroll
      for (int q = 0; q < 4; ++q)
#pragma unroll
        for (int r = 0; r < 4; ++r)
          acc[q][r] = fmaf(av[q], zv[r], acc[q][r]);
    }
    __syncthreads();
  }
  float* Cb = C + bz * batchC + n0 + tn * 4;
#pragma unroll
  for (int q = 0; q < 4; ++q) {
    int m = m0 + tm * 4 + q;
    float bv = BIAS ? (bia[m] + bib[m]) : 0.f;
    float4 v;
    v.x = acc[q][0] + bv; v.y = acc[q][1] + bv;
    v.z = acc[q][2] + bv; v.w = acc[q][3] + bv;
    *(float4*)(Cb + (long)m * ldc) = v;
  }
}

// ---- Persistent fused recurrence: all 100 steps in ONE kernel. ----
// Cooperative launch => all 256 blocks co-resident (1 block/CU).
// Block bx owns hh pair (2bx, 2bx+1). Wave w = 64-k partition; computes
// both hh (8 accs). WhhG addresses wave-uniform -> s_load path, sL1-hot.
//
// Barrier WITHOUT L2 flush/invalidate (the round-2 15 us/step killer):
//  - Hbuf[t+1] stores are relaxed agent-scope atomics (sc1 write-through
//    to MALL; no dirty L2 line). Fbuf/Dbuf/cT stay cached (read only
//    after kernel end; implicit end-of-kernel release flushes them).
//  - __syncthreads drains each wave's vmcnt => h stores visible at MALL
//    before tid0's RELAXED flag store (no buffer_wbl2).
//  - Poll flags with relaxed agent loads (bypass stale caches).
//  - NO acquire fence: Hbuf[t+1] lines are fresh addresses, never cached
//    by any L1/L2 this launch (caches invalidated at kernel start), so
//    next step's normal vector loads miss and fetch the fresh MALL copy
//    (then L2-reused by sibling blocks on the XCD).
__global__ __launch_bounds__(512, 4) void lstm_rec(
    const float* __restrict__ G_T, const float* __restrict__ WhhG,
    float* __restrict__ Hbuf, float* __restrict__ cT,
    float* __restrict__ Fbuf, float* __restrict__ Dbuf,
    int* __restrict__ bar) {
  __shared__ float red[8][8][64];  // [kp][gate-row j][b]
  int tid = threadIdx.x;
  int lane = tid & 63;
  int wave = __builtin_amdgcn_readfirstlane(tid >> 6);  // 0..7 = k-partition
  int bx = blockIdx.x;
  const float* wp = WhhG + (long)(wave * 64) * G4H + bx * 8;
  int h2 = tid >> 6;  // 0/1 for tid<128
  int b = tid & 63;
  float creg = 0.f;
  if (tid < 128) creg = cT[(bx * 2 + h2) * BB + b];

  // Prefetch step-0 x-gate precomputes (G_T is static during this kernel).
  float gpre0 = 0.f, gpre1 = 0.f, gpre2 = 0.f, gpre3 = 0.f;
  if (tid < 128) {
    const float* gp = G_T + (bx * 2 + h2) * BB + b;
    gpre0 = gp[0l * HH * BB];
    gpre1 = gp[1l * HH * BB];
    gpre2 = gp[2l * HH * BB];
    gpre3 = gp[3l * HH * BB];
  }

  for (int t = 0; t < TT; ++t) {
    // Partial dot products over this wave's 64 k, both hh, 4 gates each.
    const float* hp = Hbuf + (long)t * (HH * BB) + (wave * 64) * BB + lane;
    float a0 = 0.f, a1 = 0.f, a2 = 0.f, a3 = 0.f;
    float a4 = 0.f, a5 = 0.f, a6 = 0.f, a7 = 0.f;
#pragma unroll 4
    for (int k = 0; k < 64; ++k) {
      float h = hp[(long)k * BB];
      float4 w0 = *(const float4*)(wp + (long)k * G4H);
      float4 w1 = *(const float4*)(wp + (long)k * G4H + 4);
      a0 = fmaf(w0.x, h, a0); a1 = fmaf(w0.y, h, a1);
      a2 = fmaf(w0.z, h, a2); a3 = fmaf(w0.w, h, a3);
      a4 = fmaf(w1.x, h, a4); a5 = fmaf(w1.y, h, a5);
      a6 = fmaf(w1.z, h, a6); a7 = fmaf(w1.w, h, a7);
    }
    red[wave][0][lane] = a0; red[wave][1][lane] = a1;
    red[wave][2][lane] = a2; red[wave][3][lane] = a3;
    red[wave][4][lane] = a4; red[wave][5][lane] = a5;
    red[wave][6][lane] = a6; red[wave][7][lane] = a7;
    __syncthreads();
    if (tid < 128) {
      float g0 = gpre0, g1 = gpre1, g2 = gpre2, g3 = gpre3;
#pragma unroll
      for (int kp = 0; kp < 8; ++kp) {
        g0 += red[kp][h2 * 4 + 0][b];
        g1 += red[kp][h2 * 4 + 1][b];
        g2 += red[kp][h2 * 4 + 2][b];
        g3 += red[kp][h2 * 4 + 3][b];
      }
      float ig = 1.f / (1.f + expf(-g0));
      float fg = 1.f / (1.f + expf(-g1));
      float gg = tanhf(g2);
      float og = 1.f / (1.f + expf(-g3));
      int idx = (bx * 2 + h2) * BB + b;
      float co = creg;
      float cy = fg * co + ig * gg;
      creg = cy;
      // Write-through (agent-relaxed) so the h value is at MALL once this
      // wave's vmcnt drains — no L2 dirty line, no wbl2 needed.
      __hip_atomic_store(&Hbuf[(long)(t + 1) * (HH * BB) + idx],
                         og * tanhf(cy), __ATOMIC_RELAXED,
                         __HIP_MEMORY_SCOPE_AGENT);
      Fbuf[(long)t * (HH * BB) + idx] = fg;
      float* dp = Dbuf + (long)t * (G3H * BB) + idx;
      dp[0] = gg * ig * (1.f - ig);
      dp[HH * BB] = co * fg * (1.f - fg);
      dp[2 * HH * BB] = ig * (1.f - gg * gg);
    }
    // syncthreads: every wave drains vmcnt before s_barrier => all h
    // write-throughs are at MALL when any thread passes here.
    __syncthreads();
    if (t < TT - 1) {
      if (tid == 0)
        __hip_atomic_store(&bar[bx], t + 1, __ATOMIC_RELAXED,
                           __HIP_MEMORY_SCOPE_AGENT);
      // Prefetch next step's x-gate precomputes; latency hides under the
      // barrier wait (normal cached loads, G_T is static).
      if (tid < 128) {
        const float* gp =
            G_T + (long)(t + 1) * (G4H * BB) + (bx * 2 + h2) * BB + b;
        gpre0 = gp[0l * HH * BB];
        gpre1 = gp[1l * HH * BB];
        gpre2 = gp[2l * HH * BB];
        gpre3 = gp[3l * HH * BB];
      }
      if (tid < 64) {
        int tgt = t + 1;
        while (true) {
          int v0 = __hip_atomic_load(&bar[lane], __ATOMIC_RELAXED,
                                     __HIP_MEMORY_SCOPE_AGENT);
          int v1 = __hip_atomic_load(&bar[lane + 64], __ATOMIC_RELAXED,
                                     __HIP_MEMORY_SCOPE_AGENT);
          int v2 = __hip_atomic_load(&bar[lane + 128], __ATOMIC_RELAXED,
                                     __HIP_MEMORY_SCOPE_AGENT);
          int v3 = __hip_atomic_load(&bar[lane + 192], __ATOMIC_RELAXED,
                                     __HIP_MEMORY_SCOPE_AGENT);
          bool ok = (v0 >= tgt) && (v1 >= tgt) && (v2 >= tgt) && (v3 >= tgt);
          if (__all(ok)) break;
          __builtin_amdgcn_s_sleep(1);
        }
      }
      asm volatile("" ::: "memory");  // compiler ordering; hw order via
      __syncthreads();                // the barrier below
    }
  }
  if (tid < 128) cT[(bx * 2 + h2) * BB + b] = creg;
}

// Backward suffix scan: Dbuf[t] *= P_t; also emits ev_b.
__global__ __launch_bounds__(256) void suffix_scale(float* __restrict__ Dbuf,
                                                    const float* __restrict__ Fbuf,
                                                    float* __restrict__ evb) {
  int g = blockIdx.x * 256 + threadIdx.x;
  int b = g & 63, hh = g >> 6;
  float P = 1.f, e0 = 0.f, e1 = 0.f, e2 = 0.f;
#pragma unroll 2
  for (int t = TT - 1; t >= 0; --t) {
    float* dp = Dbuf + (long)t * (G3H * BB) + hh * BB + b;
    float v0 = dp[0] * P, v1 = dp[HH * BB] * P, v2 = dp[2 * HH * BB] * P;
    dp[0] = v0; dp[HH * BB] = v1; dp[2 * HH * BB] = v2;
    e0 += v0; e1 += v1; e2 += v2;
    P *= Fbuf[(long)t * (HH * BB) + hh * BB + b];
  }
  evb[b * G3H + hh] = e0;
  evb[b * G3H + HH + hh] = e1;
  evb[b * G3H + 2 * HH + hh] = e2;
}

extern "C" void kernel_launch(void* const* d_in, const int* in_sizes, int n_in,
                              void* d_out, int out_size, void* d_ws, size_t ws_size,
                              hipStream_t stream) {
  const float* x   = (const float*)d_in[0];  // [T][B][I]
  const float* h0  = (const float*)d_in[1];  // [B][H]
  const float* c0  = (const float*)d_in[2];  // [B][H]
  const float* Wih = (const float*)d_in[3];  // [4H][I]
  const float* Whh = (const float*)d_in[4];  // [4H][H]
  const float* bih = (const float*)d_in[5];
  const float* bhh = (const float*)d_in[6];
  float* out = (float*)d_out;
  float* ws = (float*)d_ws;

  float* G_T   = ws + OFF_GT;
  float* DbufT = ws + OFF_GT;    // aliases G_T (G_T dead after step loop)
  float* Hbuf  = ws + OFF_HBUF;
  float* Fbuf  = ws + OFF_FBUF;
  float* Dbuf  = ws + OFF_DBUF;
  float* cT    = ws + OFF_CT;
  float* xT    = ws + OFF_XT;
  float* WhhG  = ws + OFF_XT;    // aliases xT (xT dead after gx GEMM)
  float* WihT  = ws + OFF_WIHT;
  int*   bar   = (int*)(ws + OFF_WIHT);  // aliases WihT (dead after gx GEMM)
  float* WhhT  = ws + OFF_WHHT;

  // ---- prep transposes ----
  tp64<<<dim3(II / 64, G4H / 64, 1), 256, 0, stream>>>(Wih, WihT, G4H, II, 0, 0);
  tp64<<<dim3(HH / 64, G4H / 64, 1), 256, 0, stream>>>(Whh, WhhT, G4H, HH, 0, 0);
  tp64<<<dim3(II / 64, 1, TT), 256, 0, stream>>>(x, xT, BB, II, BB * II, BB * II);
  tp64<<<dim3(HH / 64, 1, 1), 256, 0, stream>>>(h0, Hbuf, BB, HH, 0, 0);
  tp64<<<dim3(HH / 64, 1, 1), 256, 0, stream>>>(c0, cT, BB, HH, 0, 0);

  // ---- G = x @ Wih^T + biases, layout [t][j][b] ----
  // C[m=j 2048][n=b 64] = sum_k WihT[k][j] * xT[t][k][b], K=256
  gemm_tn<64, 4, true, false><<<dim3(G4H / 64, 1, TT), 256, 0, stream>>>(
      WihT, 0, G4H, xT, (long)II * BB, BB, nullptr, 0,
      G_T, (long)G4H * BB, BB, bih, bhh);

  // ---- gate-interleave Whh + zero barrier slots (after gx: WihT/xT dead) ----
  make_whhg<<<dim3(HH * G4H / 256, 1, 1), 256, 0, stream>>>(WhhT, WhhG, bar);

  // ---- fused sequential recurrence: ONE cooperative kernel, 100 steps ----
  {
    const float* a_gt = G_T;
    const float* a_wg = WhhG;
    float* a_hb = Hbuf;
    float* a_ct = cT;
    float* a_fb = Fbuf;
    float* a_db = Dbuf;
    int* a_bar = bar;
    void* args[] = {(void*)&a_gt, (void*)&a_wg, (void*)&a_hb, (void*)&a_ct,
                    (void*)&a_fb, (void*)&a_db, (void*)&a_bar};
    hipLaunchCooperativeKernel((const void*)lstm_rec, dim3(NBLK), dim3(512),
                               args, 0, stream);
  }

  // ---- backward suffix scaling (+ ev_b) ----
  suffix_scale<<<dim3(HH * BB / 256, 1, 1), 256, 0, stream>>>(Dbuf, Fbuf,
                                                              out + O_EVB);

  // ---- Dbuf [T*3H][B] -> DbufT [B][T*3H] (into dead G_T region) ----
  tp64<<<dim3(1, TT * G3H / 64, 1), 256, 0, stream>>>(Dbuf, DbufT, TT * G3H, BB,
                                                      0, 0);

  // ---- outputs + cx ----
  tp64<<<dim3(1, HH / 64, TT), 256, 0, stream>>>(Hbuf + HH * BB, out + O_OUT,
                                                 HH, BB, HH * BB, HH * BB);
  tp64<<<dim3(1, HH / 64, 1), 256, 0, stream>>>(cT, out + O_CX, HH, BB, 0, 0);

  // ---- ev_ih[b][j][i] = sum_t DbufT[b][t][j] * x[t][b][i], K=100 ----
  gemm_tn<20, 5, false, false><<<dim3(G3H / 64, II / 64, BB), 256, 0, stream>>>(
      DbufT, (long)TT * G3H, G3H, x, (long)II, (long)BB * II, nullptr, 0,
      out + O_EVIH, (long)G3H * II, II, nullptr, nullptr);

  // ---- ev_hh[b][j][k] = sum_t DbufT[b][t][j] * h_{t-1}[b][k], K=100 ----
  gemm_tn<20, 5, false, true><<<dim3(G3H / 64, HH / 64, BB), 256, 0, stream>>>(
      DbufT, (long)TT * G3H, G3H, out + O_OUT, (long)HH, (long)BB * HH,
      h0, (long)HH,
      out + O_EVHH, (long)G3H * HH, HH, nullptr, nullptr);
}